// Round 9
// baseline (6683.437 us; speedup 1.0000x reference)
//
#include <hip/hip_runtime.h>
#include <hip/hip_cooperative_groups.h>
#include <utility>

namespace cg = cooperative_groups;

// Problem constants (from reference)
#define NB   32
#define CH   2
#define HH   640
#define WW   640
#define HW   (HH * WW)        // 409600 pixels per image
#define NHW  (NB * HW)        // 13107200 pixels total
#define PLANE (CH * HW)       // 819200 floats per image, planar
#define HALF (NB * PLANE)     // 26214400 floats per output tensor

#define BLK_PX       512                   // pixels per block (256 thr x 2 px)
#define QPB          (BLK_PX / 2)          // 256 float4 (pixel-pair) slots/block
#define BLKS_PER_IMG (HW / BLK_PX)         // 800
#define GRID_STEP    (NB * BLKS_PER_IMG)   // 25600

// 8B-aligned 4-float vector (row-pair load may sit at odd-pixel offsets).
struct alignas(8) f4u { float x, y, z, w; };
// 8B-aligned 2-float vector.
struct alignas(8) f2a { float x, y; };
// 4B-aligned 2-float vector (planar row-pair load).
struct alignas(4) f2u { float x, y; };

// Session facts (hard-won):
//  - nt loads AND nt stores both regress badly on gfx950 (rounds 1, 7). Never.
//  - Coordinate math must follow reference order with the REAL ig bits
//    (round 3: ulp-level recompute -> absmax 1.06 FAIL).
//  - Separable ig tables / direct row-0+col-0 ig loads (same bits) removed the
//    105 MB/step ig stream: -24% (round 6).
//  - Serpentine step ordering: neutral (round 8). Forward everywhere.

// Separable identity-grid tables (fallback path only).
__device__ float g_xs[WW];
__device__ float g_ys[HH];

__global__ void k_extract(const float2* __restrict__ ig) {
    int i = blockIdx.x * blockDim.x + threadIdx.x;
    if (i < WW) g_xs[i] = ig[i].x;          // row 0: x varies, .x = xs[i]
    if (i < HH) g_ys[i] = ig[i * WW].y;     // col 0: y varies, .y = ys[i]
}

// Virtual block -> (image, pixel-quad), image pinned to XCD (vb%8 heuristic).
// Callers guarantee stride is a multiple of 8, so vb&7 is invariant per block.
__device__ __forceinline__ void decode_vb(int vb, int& n, int& q) {
    int xcd = vb & 7;
    int slot = vb >> 3;                  // 0..3199
    int img_round = slot / BLKS_PER_IMG; // 0..3
    int blk = slot - img_round * BLKS_PER_IMG;
    n = img_round * 8 + xcd;             // image -> fixed XCD
    q = blk * QPB + threadIdx.x;         // float4 (pixel-pair) index in image
}

// Bilinear sample, border clamp, align_corners=True, reference-order coords.
// Row-pair loads: v00,v01 are 16 contiguous bytes -> one dwordx4 per row
// (halves gather transactions).  Edge x0=W-1 via base shift (t hits 1.0,
// lerp(v638,v639,1)==v639 bitwise).
__device__ __forceinline__ float2 bilin_pair(const float2* __restrict__ img,
                                             float gx, float gy) {
    float fx = (gx + 1.0f) * (0.5f * (float)(WW - 1));
    float fy = (gy + 1.0f) * (0.5f * (float)(HH - 1));
    fx = fminf(fmaxf(fx, 0.0f), (float)(WW - 1));
    fy = fminf(fmaxf(fy, 0.0f), (float)(HH - 1));
    float x0f = floorf(fx);
    float y0f = floorf(fy);
    int x0 = (int)x0f;
    int y0 = (int)y0f;
    int y1 = min(y0 + 1, HH - 1);
    int xb = min(x0, WW - 2);
    float t    = fx - (float)xb;     // == wx interior; == 1.0 at right edge
    float omt  = 1.0f - t;
    float wy   = fy - y0f;
    float omwy = 1.0f - wy;
    const f4u* r0 = (const f4u*)(img + y0 * WW + xb);
    const f4u* r1 = (const f4u*)(img + y1 * WW + xb);
    f4u a = *r0;   // v00.x v00.y v01.x v01.y
    f4u b = *r1;   // v10.x v10.y v11.x v11.y
    float topx = a.x * omt + a.z * t;
    float topy = a.y * omt + a.w * t;
    float botx = b.x * omt + b.z * t;
    float boty = b.y * omt + b.w * t;
    return make_float2(topx * omwy + botx * wy, topy * omwy + boty * wy);
}

// Planar-source variant for step 1 (scale s=2^-32 applied after the lerp;
// power-of-2 scale commutes bitwise with the lerp).
__device__ __forceinline__ float2 bilin_planar_pair(const float* __restrict__ vx,
                                                    const float* __restrict__ vy,
                                                    float gx, float gy, float s) {
    float fx = (gx + 1.0f) * (0.5f * (float)(WW - 1));
    float fy = (gy + 1.0f) * (0.5f * (float)(HH - 1));
    fx = fminf(fmaxf(fx, 0.0f), (float)(WW - 1));
    fy = fminf(fmaxf(fy, 0.0f), (float)(HH - 1));
    float x0f = floorf(fx);
    float y0f = floorf(fy);
    int x0 = (int)x0f;
    int y0 = (int)y0f;
    int y1 = min(y0 + 1, HH - 1);
    int xb = min(x0, WW - 2);
    float t    = fx - (float)xb;
    float omt  = 1.0f - t;
    float wy   = fy - y0f;
    float omwy = 1.0f - wy;
    int r0 = y0 * WW + xb;
    int r1 = y1 * WW + xb;
    f2u ax0 = *(const f2u*)(vx + r0);
    f2u ax1 = *(const f2u*)(vx + r1);
    f2u ay0 = *(const f2u*)(vy + r0);
    f2u ay1 = *(const f2u*)(vy + r1);
    float topx = ax0.x * omt + ax0.y * t;
    float topy = ay0.x * omt + ay0.y * t;
    float botx = ax1.x * omt + ax1.y * t;
    float boty = ay1.x * omt + ay1.y * t;
    return make_float2((topx * omwy + botx * wy) * s,
                       (topy * omwy + boty * wy) * s);
}

// Identity-grid values for pixel pair p,p+1, read DIRECTLY from ig (bit-exact;
// row 0 gives xs[x], xs[x+1] in one 16B load; col 0 gives ys[y]).  The touched
// ig lines (5 KB row + 80 KB of col-0 lines) stay cache-hot -- this is NOT the
// 105 MB/step ig stream that round 6 eliminated.
__device__ __forceinline__ void grid_pair_ig(const float2* __restrict__ ig,
                                             int p, float& gx0, float& gx1, float& gy) {
    int y = p / WW;
    int x = p - y * WW;
    f4u gg = *(const f4u*)(ig + x);   // (xs[x], ys0, xs[x+1], ys0)
    gx0 = gg.x;
    gx1 = gg.z;
    gy  = ig[y * WW].y;
}

// Table variant (fallback kernels).
__device__ __forceinline__ void grid_pair_tab(int p, float& gx0, float& gx1, float& gy) {
    int y = p / WW;
    int x = p - y * WW;
    f2a gx2 = *(const f2a*)(g_xs + x);
    gx0 = gx2.x;
    gx1 = gx2.y;
    gy  = g_ys[y];
}

// ---------- shared phase bodies ----------

__device__ __forceinline__ void body_init_step1(const float* __restrict__ v,
                                                const float2* __restrict__ ig,
                                                float2* __restrict__ out, int vb) {
    int n, q;
    decode_vb(vb, n, q);
    const float* vx = v + (size_t)n * PLANE;
    const float* vy = vx + HW;
    int p = q * 2;
    const float s = 2.3283064365386963e-10f;  // 2^-32, exact
    float2 dvx = *(const float2*)(vx + p);
    float2 dvy = *(const float2*)(vy + p);
    float gx0, gx1, gy;
    grid_pair_ig(ig, p, gx0, gx1, gy);
    float dx0 = dvx.x * s, dy0 = dvy.x * s;
    float dx1 = dvx.y * s, dy1 = dvy.y * s;

    float2 s0 = bilin_planar_pair(vx, vy, gx0 + dx0, gy + dy0, s);
    float2 s1 = bilin_planar_pair(vx, vy, gx1 + dx1, gy + dy1, s);

    float4* out4 = (float4*)(out + (size_t)n * HW);
    out4[q] = make_float4(dx0 + s0.x, dy0 + s0.y, dx1 + s1.x, dy1 + s1.y);
}

__device__ __forceinline__ void body_step(const float2* __restrict__ in,
                                          const float2* __restrict__ ig,
                                          float2* __restrict__ out, int vb) {
    int n, q;
    decode_vb(vb, n, q);
    const float2* img  = in + (size_t)n * HW;
    const float4* img4 = (const float4*)img;
    float4 d = img4[q];
    float gx0, gx1, gy;
    grid_pair_ig(ig, q * 2, gx0, gx1, gy);

    float2 s0 = bilin_pair(img, gx0 + d.x, gy + d.y);
    float2 s1 = bilin_pair(img, gx1 + d.z, gy + d.w);

    float4* out4 = (float4*)(out + (size_t)n * HW);
    out4[q] = make_float4(d.x + s0.x, d.y + s0.y, d.z + s1.x, d.w + s1.y);
}

__device__ __forceinline__ void body_final(const float2* __restrict__ in,
                                           const float2* __restrict__ ig,
                                           float* __restrict__ trans,
                                           float* __restrict__ disp, int vb) {
    int n, q;
    decode_vb(vb, n, q);
    const float2* img  = in + (size_t)n * HW;
    const float4* img4 = (const float4*)img;
    float4 d = img4[q];
    int p = q * 2;
    float gx0, gx1, gy;
    grid_pair_ig(ig, p, gx0, gx1, gy);

    float2 s0 = bilin_pair(img, gx0 + d.x, gy + d.y);
    float2 s1 = bilin_pair(img, gx1 + d.z, gy + d.w);

    float dx0 = d.x + s0.x, dy0 = d.y + s0.y;
    float dx1 = d.z + s1.x, dy1 = d.w + s1.y;

    float* dispn  = disp  + (size_t)n * PLANE;
    float* transn = trans + (size_t)n * PLANE;
    *(float2*)(dispn + p)       = make_float2(dx0, dx1);
    *(float2*)(dispn + HW + p)  = make_float2(dy0, dy1);
    *(float2*)(transn + p)      = make_float2(dx0 + gx0, dx1 + gx1);
    *(float2*)(transn + HW + p) = make_float2(dy0 + gy,  dy1 + gy);
}

// ---------- cooperative mega-kernel: all 32 steps + epilogue, one launch ----
// Persistent blocks grid-stride the 25600 virtual blocks; gridDim.x is a
// multiple of 8 so vb&7 (XCD pin) is invariant per block.  Correctness across
// XCDs rests on grid.sync()'s device-scope fence, NOT on the pinning.
__global__ __launch_bounds__(256, 4) void k_mega(const float* __restrict__ v,
                                                 const float2* __restrict__ ig,
                                                 float2* h0, float2* ws,
                                                 float* trans, float* disp) {
    cg::grid_group grid = cg::this_grid();
    const int stride = gridDim.x;

    // Phase 1: init + step 1 -> ws (disp1)
    for (int vb = blockIdx.x; vb < GRID_STEP; vb += stride)
        body_init_step1(v, ig, ws, vb);
    grid.sync();

    // Phases 2..31: ping-pong ws <-> h0; disp_s for odd s lands in ws.
    float2* a = ws;   // holds disp_{s-1} at loop top
    float2* b = h0;
    #pragma unroll 1
    for (int s = 2; s <= 31; ++s) {
        for (int vb = blockIdx.x; vb < GRID_STEP; vb += stride)
            body_step(a, ig, b, vb);
        float2* t = a; a = b; b = t;   // a now holds disp_s
        grid.sync();
    }

    // Final step 32 fused with epilogue: a == ws (disp31) -> planar outputs.
    for (int vb = blockIdx.x; vb < GRID_STEP; vb += stride)
        body_final(a, ig, trans, disp, vb);
}

// ---------- multi-dispatch fallback (round-6 proven path) ----------

__global__ __launch_bounds__(256) void k_init_step1(const float* __restrict__ v,
                                                    float2* __restrict__ out) {
    int n, q;
    decode_vb(blockIdx.x, n, q);
    const float* vx = v + (size_t)n * PLANE;
    const float* vy = vx + HW;
    int p = q * 2;
    const float s = 2.3283064365386963e-10f;
    float2 dvx = *(const float2*)(vx + p);
    float2 dvy = *(const float2*)(vy + p);
    float gx0, gx1, gy;
    grid_pair_tab(p, gx0, gx1, gy);
    float dx0 = dvx.x * s, dy0 = dvy.x * s;
    float dx1 = dvx.y * s, dy1 = dvy.y * s;
    float2 s0 = bilin_planar_pair(vx, vy, gx0 + dx0, gy + dy0, s);
    float2 s1 = bilin_planar_pair(vx, vy, gx1 + dx1, gy + dy1, s);
    float4* out4 = (float4*)(out + (size_t)n * HW);
    out4[q] = make_float4(dx0 + s0.x, dy0 + s0.y, dx1 + s1.x, dy1 + s1.y);
}

template<int STEP>
__global__ __launch_bounds__(256) void k_step(const float2* __restrict__ in,
                                              float2* __restrict__ out) {
    int n, q;
    decode_vb(blockIdx.x, n, q);
    const float2* img  = in + (size_t)n * HW;
    const float4* img4 = (const float4*)img;
    float4 d = img4[q];
    float gx0, gx1, gy;
    grid_pair_tab(q * 2, gx0, gx1, gy);
    float2 s0 = bilin_pair(img, gx0 + d.x, gy + d.y);
    float2 s1 = bilin_pair(img, gx1 + d.z, gy + d.w);
    float4* out4 = (float4*)(out + (size_t)n * HW);
    out4[q] = make_float4(d.x + s0.x, d.y + s0.y, d.z + s1.x, d.w + s1.y);
}

__global__ __launch_bounds__(256) void k_step_final(const float2* __restrict__ in,
                                                    float* __restrict__ trans,
                                                    float* __restrict__ disp) {
    int n, q;
    decode_vb(blockIdx.x, n, q);
    const float2* img  = in + (size_t)n * HW;
    const float4* img4 = (const float4*)img;
    float4 d = img4[q];
    int p = q * 2;
    float gx0, gx1, gy;
    grid_pair_tab(p, gx0, gx1, gy);
    float2 s0 = bilin_pair(img, gx0 + d.x, gy + d.y);
    float2 s1 = bilin_pair(img, gx1 + d.z, gy + d.w);
    float dx0 = d.x + s0.x, dy0 = d.y + s0.y;
    float dx1 = d.z + s1.x, dy1 = d.w + s1.y;
    float* dispn  = disp  + (size_t)n * PLANE;
    float* transn = trans + (size_t)n * PLANE;
    *(float2*)(dispn + p)       = make_float2(dx0, dx1);
    *(float2*)(dispn + HW + p)  = make_float2(dy0, dy1);
    *(float2*)(transn + p)      = make_float2(dx0 + gx0, dx1 + gx1);
    *(float2*)(transn + HW + p) = make_float2(dy0 + gy,  dy1 + gy);
}

// ---------- no-workspace fallback kernels ----------

__global__ void k_init(const float* __restrict__ v, float2* __restrict__ out) {
    int idx = blockIdx.x * blockDim.x + threadIdx.x;
    if (idx >= NHW) return;
    int n = idx / HW;
    int p = idx - n * HW;
    const float s = 2.3283064365386963e-10f;
    float dx = v[n * PLANE + p] * s;
    float dy = v[n * PLANE + HW + p] * s;
    out[idx] = make_float2(dx, dy);
}

__global__ __launch_bounds__(256) void k_deinterleave(const float2* __restrict__ in,
                                                      float* __restrict__ disp) {
    int i = blockIdx.x * blockDim.x + threadIdx.x;
    if (i >= NHW / 2) return;
    int n = i / (HW / 2);
    int qp = i - n * (HW / 2);
    int p = qp * 2;
    const float4* in4 = (const float4*)(in + (size_t)n * HW);
    float4 d = in4[qp];
    float* dispn = disp + (size_t)n * PLANE;
    *(float2*)(dispn + p)      = make_float2(d.x, d.z);
    *(float2*)(dispn + HW + p) = make_float2(d.y, d.w);
}

__global__ __launch_bounds__(256) void k_trans(const float* __restrict__ disp,
                                               const float2* __restrict__ ig,
                                               float* __restrict__ trans) {
    int i = blockIdx.x * blockDim.x + threadIdx.x;
    if (i >= NHW / 2) return;
    int n = i / (HW / 2);
    int qp = i - n * (HW / 2);
    int p = qp * 2;
    const float4* ig4 = (const float4*)ig;
    float4 g = ig4[qp];
    const float* dispn = disp + (size_t)n * PLANE;
    float* transn = trans + (size_t)n * PLANE;
    float2 dx = *(const float2*)(dispn + p);
    float2 dy = *(const float2*)(dispn + HW + p);
    *(float2*)(transn + p)      = make_float2(dx.x + g.x, dx.y + g.z);
    *(float2*)(transn + HW + p) = make_float2(dy.x + g.y, dy.y + g.w);
}

// ---------- launch helpers (fallback) ----------

template<int I>
static inline void launch_mid(float2* h0, float2* ws, hipStream_t s) {
    const float2* src = (I & 1) ? (const float2*)h0 : (const float2*)ws;
    float2* dst       = (I & 1) ? ws : h0;
    k_step<I><<<GRID_STEP, 256, 0, s>>>(src, dst);
}

template<int... Is>
static inline void launch_mids(std::integer_sequence<int, Is...>,
                               float2* h0, float2* ws, hipStream_t s) {
    (launch_mid<Is + 2>(h0, ws, s), ...);
}

template<int I>
static inline void launch_fb(float2* h0, float2* h1, hipStream_t s) {
    const float2* src = (I & 1) ? (const float2*)h0 : (const float2*)h1;
    float2* dst       = (I & 1) ? h1 : h0;
    k_step<I><<<GRID_STEP, 256, 0, s>>>(src, dst);
}

template<int... Is>
static inline void launch_fbs(std::integer_sequence<int, Is...>,
                              float2* h0, float2* h1, hipStream_t s) {
    (launch_fb<Is + 1>(h0, h1, s), ...);
}

extern "C" void kernel_launch(void* const* d_in, const int* in_sizes, int n_in,
                              void* d_out, int out_size, void* d_ws, size_t ws_size,
                              hipStream_t stream) {
    const float*  v  = (const float*)d_in[0];
    const float2* ig = (const float2*)d_in[1];
    float* out = (float*)d_out;

    float2* h0 = (float2*)out;           // transformation slot
    float2* h1 = (float2*)(out + HALF);  // displacement slot

    const size_t need_ws = (size_t)NHW * sizeof(float2);  // 104.9 MB

    // Size the cooperative grid once (host-side occupancy query; no stream op).
    static int s_nblk = -2;  // -2 uninit, 0 disabled
    if (s_nblk == -2) {
        int occ = 0;
        hipError_t e = hipOccupancyMaxActiveBlocksPerMultiprocessor(&occ, k_mega, 256, 0);
        if (e != hipSuccess || occ <= 0) {
            s_nblk = 0;
        } else {
            long nb = (long)occ * 256;     // 256 CUs on MI355X
            if (nb > GRID_STEP) nb = GRID_STEP;
            nb = (nb / 8) * 8;             // keep vb&7 invariant per block
            s_nblk = (nb >= 64) ? (int)nb : 0;
        }
    }

    if (ws_size >= need_ws && s_nblk > 0) {
        float2* wsbuf = (float2*)d_ws;
        float* trans = out;
        float* disp  = out + HALF;
        void* args[] = { (void*)&v, (void*)&ig, (void*)&h0, (void*)&wsbuf,
                         (void*)&trans, (void*)&disp };
        hipError_t e = hipLaunchCooperativeKernel((const void*)k_mega,
                                                  dim3(s_nblk), dim3(256),
                                                  args, 0, stream);
        if (e == hipSuccess) return;
        s_nblk = 0;  // coop unsupported here -> permanent fallback
    }

    if (ws_size >= need_ws) {
        float2* wsbuf = (float2*)d_ws;
        k_extract<<<3, 256, 0, stream>>>(ig);
        k_init_step1<<<GRID_STEP, 256, 0, stream>>>(v, wsbuf);
        launch_mids(std::make_integer_sequence<int, 30>{}, h0, wsbuf, stream);
        k_step_final<<<GRID_STEP, 256, 0, stream>>>(wsbuf, out, out + HALF);
    } else {
        const int threads = 256;
        const int blocks  = (NHW + threads - 1) / threads;
        k_extract<<<3, 256, 0, stream>>>(ig);
        k_init<<<blocks, threads, 0, stream>>>(v, h0);
        launch_fbs(std::make_integer_sequence<int, 32>{}, h0, h1, stream);
        const int blocks2 = (NHW / 2 + threads - 1) / threads;
        k_deinterleave<<<blocks2, threads, 0, stream>>>(h0, out + HALF);
        k_trans<<<blocks2, threads, 0, stream>>>(out + HALF, ig, out);
    }
}